// Round 6
// baseline (41.707 us; speedup 1.0000x reference)
//
#include <hip/hip_runtime.h>
#include <math.h>

// Problem constants (fixed shapes from reference)
#define BATCH   8
#define HGRID   64
#define WGRID   64
#define DDIM    256
#define NPTS    1024
#define ROWS    65          // HGRID + 1 (NaN pad row 0)
#define COLS    65
#define KWIN    15          // (2*R_WIN+1)*(2*C_WIN+1) = 3*5
#define BN      (BATCH*NPTS)

#define PIDS_PER_BLK 8
#define THREADS      512    // 8 waves, 1 pid per wave in Phase B
#define PR_PITCH     260

typedef __attribute__((ext_vector_type(8))) short bf16x8;
typedef __attribute__((ext_vector_type(4))) float f32x4;

// ---------------------------------------------------------------------------
// Fused v3: per block of 8 points,
//   Phase A (no barriers): proj[8][256] = c_t rows x W_a, split-bf16 MFMA,
//     W read per-wave from global (L2-hot). Rows 8..15 of the MFMA tile are
//     duplicates (l15&7) and never stored.
//   one __syncthreads()
//   Phase B: online-softmax local attention, ONE pid per wave. No qg array:
//     each gathered q row is loaded once and folded into running (m, s, o).
// __launch_bounds__(512,8): 64-VGPR cap -> 8 waves/SIMD; grid 1024 = 4 blk/CU
// ---------------------------------------------------------------------------
__global__ __launch_bounds__(THREADS, 8) void fused_local_attn(
        const float* __restrict__ q,
        const float* __restrict__ c_t,
        const float* __restrict__ p_t,
        const float* __restrict__ W,
        float* __restrict__ out) {

    __shared__ __align__(16) float Pr[PIDS_PER_BLK][PR_PITCH]; // proj rows (8.3 KB)

    const int t    = threadIdx.x;
    const int w    = t >> 6;          // wave 0..7
    const int lane = t & 63;
    const int l15  = lane & 15;
    const int g    = lane >> 4;       // k-group 0..3
    const int pid0 = blockIdx.x * PIDS_PER_BLK;
    const int dq   = w * 32;          // this wave's 32-col d-slice

    // ---------------- Phase A: proj into LDS (no barriers) ----------------
    f32x4 acc0 = (f32x4)0.f;
    f32x4 acc1 = (f32x4)0.f;

    const float* ap  = &c_t[(size_t)(pid0 + (l15 & 7)) * DDIM + g * 8];
    const float* wp0 = &W[(size_t)(g * 8) * DDIM + dq + l15];        // df=0
    const float* wp1 = wp0 + 16;                                      // df=1

    for (int kt = 0; kt < 8; ++kt) {
        // A fragment: 8 contiguous c-values of this lane's c_t row
        const float4 a01 = *reinterpret_cast<const float4*>(ap + kt * 32);
        const float4 a23 = *reinterpret_cast<const float4*>(ap + kt * 32 + 4);
        const float af[8] = {a01.x, a01.y, a01.z, a01.w, a23.x, a23.y, a23.z, a23.w};
        union { bf16x8 v; unsigned u[4]; } AH, AL;
        #pragma unroll
        for (int i = 0; i < 4; ++i) {
            const unsigned u0 = __float_as_uint(af[2 * i]);
            const unsigned u1 = __float_as_uint(af[2 * i + 1]);
            AH.u[i] = __builtin_amdgcn_perm(u1, u0, 0x07060302u);
            const float l0 = af[2 * i]     - __uint_as_float(u0 & 0xFFFF0000u);
            const float l1 = af[2 * i + 1] - __uint_as_float(u1 & 0xFFFF0000u);
            AL.u[i] = __builtin_amdgcn_perm(__float_as_uint(l1), __float_as_uint(l0),
                                            0x07060302u);
        }

        #pragma unroll
        for (int df = 0; df < 2; ++df) {
            const float* wp = (df == 0) ? wp0 : wp1;
            float bf[8];
            #pragma unroll
            for (int i = 0; i < 8; ++i)
                bf[i] = wp[(size_t)(kt * 32 + i) * DDIM];
            union { bf16x8 v; unsigned u[4]; } BH, BL;
            #pragma unroll
            for (int i = 0; i < 4; ++i) {
                const unsigned u0 = __float_as_uint(bf[2 * i]);
                const unsigned u1 = __float_as_uint(bf[2 * i + 1]);
                BH.u[i] = __builtin_amdgcn_perm(u1, u0, 0x07060302u);
                const float l0 = bf[2 * i]     - __uint_as_float(u0 & 0xFFFF0000u);
                const float l1 = bf[2 * i + 1] - __uint_as_float(u1 & 0xFFFF0000u);
                BL.u[i] = __builtin_amdgcn_perm(__float_as_uint(l1), __float_as_uint(l0),
                                                0x07060302u);
            }
            f32x4 a = (df == 0) ? acc0 : acc1;
            a = __builtin_amdgcn_mfma_f32_16x16x32_bf16(AH.v, BH.v, a, 0, 0, 0);
            a = __builtin_amdgcn_mfma_f32_16x16x32_bf16(AH.v, BL.v, a, 0, 0, 0);
            a = __builtin_amdgcn_mfma_f32_16x16x32_bf16(AL.v, BH.v, a, 0, 0, 0);
            if (df == 0) acc0 = a; else acc1 = a;
        }
    }

    // C/D layout: col = lane&15, row = (lane>>4)*4 + reg  [m89-verified]
    // Only rows 0..7 are real points (g < 2).
    if (g < 2) {
        #pragma unroll
        for (int r = 0; r < 4; ++r) {
            Pr[g * 4 + r][dq +  0 + l15] = acc0[r];
            Pr[g * 4 + r][dq + 16 + l15] = acc1[r];
        }
    }
    __syncthreads();

    // ---------------- Phase B: online-softmax attention, 1 pid/wave -------
    const int pid = pid0 + w;
    const int b   = pid >> 10;             // / NPTS
    const float2 ppos = *reinterpret_cast<const float2*>(&p_t[pid * 2]);
    const float p0f = ppos.x;
    const float p1f = ppos.y;
    const int p0 = (int)p0f;
    const int p1 = (int)p1f;

    const float4 pr = *reinterpret_cast<const float4*>(&Pr[w][lane * 4]);

    float re[3], ce[5];
    int rowidx[3], colidx[5];
    #pragma unroll
    for (int i = 0; i < 3; ++i) {
        int rr = p0 + i;
        rr = rr > ROWS ? ROWS : rr;
        rr = (rr == ROWS) ? 0 : rr;        // % ROWS
        rowidx[i] = rr;
        const float rf = (float)(rr - 1 > 0 ? rr - 1 : 0);
        const float dr = rf - p0f;         // / R_WIN (=1)
        re[i] = __expf(-2.0f * dr * dr);
    }
    #pragma unroll
    for (int j = 0; j < 5; ++j) {
        int cc = p1 + j - 1;
        cc = cc < 0 ? 0 : (cc > COLS ? COLS : cc);
        cc = (cc == COLS) ? 0 : cc;        // % COLS
        colidx[j] = cc;
        const float cf = (float)(cc - 1 > 0 ? cc - 1 : 0);
        const float dc = (cf - p1f) * 0.5f; // / C_WIN (=2)
        ce[j] = __expf(-2.0f * dc * dc);
    }

    float m = -INFINITY;                   // running max of scores
    float s = 0.f;                         // running softmax denominator
    float ox = 0.f, oy = 0.f, oz = 0.f, ow = 0.f;  // running weighted sum

    #pragma unroll
    for (int i = 0; i < 3; ++i) {
        #pragma unroll
        for (int j = 0; j < 5; ++j) {
            const int rr = rowidx[i];
            const int cc = colidx[j];
            if ((rr != 0) && (cc != 0)) {             // wave-uniform
                const float4 v = *reinterpret_cast<const float4*>(
                    &q[((size_t)((b * HGRID + rr - 1) * WGRID + cc - 1)) * DDIM
                       + lane * 4]);
                float sc = fmaf(v.x, pr.x, fmaf(v.y, pr.y, fmaf(v.z, pr.z, v.w * pr.w)));
                #pragma unroll
                for (int off = 32; off; off >>= 1) sc += __shfl_xor(sc, off, 64);
                // online update (sc is wave-uniform after reduce)
                const float mn   = fmaxf(m, sc);
                const float corr = __expf(m - mn);    // exp(-inf)=0 on first hit
                const float e    = __expf(sc - mn);
                const float ew   = e * re[i] * ce[j];
                m = mn;
                s = fmaf(s, corr, e);
                ox = fmaf(ox, corr, ew * v.x);
                oy = fmaf(oy, corr, ew * v.y);
                oz = fmaf(oz, corr, ew * v.z);
                ow = fmaf(ow, corr, ew * v.w);
            }
        }
    }

    const float inv = 1.0f / s;
    *reinterpret_cast<float4*>(&out[(size_t)pid * DDIM + lane * 4]) =
        make_float4(ox * inv, oy * inv, oz * inv, ow * inv);
}

// ---------------------------------------------------------------------------
extern "C" void kernel_launch(void* const* d_in, const int* in_sizes, int n_in,
                              void* d_out, int out_size, void* d_ws, size_t ws_size,
                              hipStream_t stream) {
    const float* q   = (const float*)d_in[0];
    const float* c_t = (const float*)d_in[1];
    const float* p_t = (const float*)d_in[2];
    const float* W_a = (const float*)d_in[3];
    float* out = (float*)d_out;

    fused_local_attn<<<BN / PIDS_PER_BLK, THREADS, 0, stream>>>(q, c_t, p_t, W_a, out);
}